// Round 1
// baseline (936.792 us; speedup 1.0000x reference)
//
#include <hip/hip_runtime.h>
#include <stdint.h>

typedef unsigned short u16;
typedef unsigned int   u32;
typedef __attribute__((ext_vector_type(8))) short bf16x8;
typedef __attribute__((ext_vector_type(4))) float f32x4;
typedef __attribute__((ext_vector_type(4))) u32   u32x4;

// Problem constants
#define BB 4
#define SS 2048
#define DD 1024
#define HH 16
// DK = DV = 64

__device__ __forceinline__ u16 f2b(float f){
  u32 u = __builtin_bit_cast(u32, f);
  u32 r = (u + 0x7FFFu + ((u >> 16) & 1u)) >> 16;   // RNE bf16 (finite values only)
  return (u16)r;
}
__device__ __forceinline__ float b2f(u16 h){
  return __builtin_bit_cast(float, (u32)h << 16);
}

// async global->LDS, 16B per lane; lds base must be wave-uniform.
__device__ __forceinline__ void gload16(const u16* g, u16* l){
  __builtin_amdgcn_global_load_lds(
      (const __attribute__((address_space(1))) void*)(uintptr_t)g,
      (__attribute__((address_space(3))) void*)(uintptr_t)l,
      16, 0, 0);
}

// ---------------- weight transpose + bf16 convert: Wt[n][k] = bf16(W[k][n]) ---------
__global__ void transpose_cvt(const float* __restrict__ W, u16* __restrict__ Wt)
{
  __shared__ float tile[32][33];
  const int tx = threadIdx.x, ty = threadIdx.y;   // 32 x 8
  const int n0 = blockIdx.x * 32, k0 = blockIdx.y * 32;
  #pragma unroll
  for(int j = 0; j < 4; ++j)
    tile[ty + j*8][tx] = W[(size_t)(k0 + ty + j*8) * DD + n0 + tx];
  __syncthreads();
  #pragma unroll
  for(int j = 0; j < 4; ++j)
    Wt[(size_t)(n0 + ty + j*8) * DD + k0 + tx] = f2b(tile[tx][ty + j*8]);
}

// ---------------- 128x128 MFMA GEMM, K=1024, N=1024, M=8192 ------------------------
// MODE 0: C=bf16 Q  [b][h][s][dk], value*(1/8)
// MODE 1: C=bf16 K  [b][h][s][dk]
// MODE 2: C=bf16 Vt [b][h][dv][s]
// MODE 3: A is bf16 (attnout), C=f32 tmp[m][n] (+bias)
template<int MODE>
__global__ __launch_bounds__(256)
void gemm128(const void* __restrict__ Ain, const u16* __restrict__ Bt,
             const float* __restrict__ bias, void* __restrict__ Cout)
{
  __shared__ __align__(16) u16 As[128*32];
  __shared__ __align__(16) u16 Bs[128*32];
  const int tid = threadIdx.x;
  const int w = tid >> 6, ln = tid & 63, g = ln >> 4, c16 = ln & 15;
  const int m0 = blockIdx.y * 128, n0 = blockIdx.x * 128;
  const int wr = (w >> 1) * 64, wc = (w & 1) * 64;

  f32x4 acc[4][4] = {};

  for(int kt = 0; kt < 1024; kt += 32){
    __syncthreads();
    // ---- stage B tile: Bs[n][k] <- Bt[n0+n][kt+k], via global_load_lds x2/thread
    {
      const int f0 = w * 2;
      #pragma unroll
      for(int j = 0; j < 2; ++j){
        int e = ((f0 + j) * 64 + ln) * 8;
        gload16(Bt + (size_t)(n0 + (e >> 5)) * 1024 + kt + (e & 31),
                Bs + (size_t)(f0 + j) * 512);
      }
    }
    // ---- stage A tile
    if (MODE < 3){
      const float* A = (const float*)Ain;
      const int row = tid >> 1, cb = (tid & 1) * 16;
      const float4* gp = (const float4*)(A + (size_t)(m0 + row) * 1024 + kt + cb);
      float4 v0 = gp[0], v1 = gp[1], v2 = gp[2], v3 = gp[3];
      u32x4 o0, o1;
      o0.x = f2b(v0.x) | ((u32)f2b(v0.y) << 16);
      o0.y = f2b(v0.z) | ((u32)f2b(v0.w) << 16);
      o0.z = f2b(v1.x) | ((u32)f2b(v1.y) << 16);
      o0.w = f2b(v1.z) | ((u32)f2b(v1.w) << 16);
      o1.x = f2b(v2.x) | ((u32)f2b(v2.y) << 16);
      o1.y = f2b(v2.z) | ((u32)f2b(v2.w) << 16);
      o1.z = f2b(v3.x) | ((u32)f2b(v3.y) << 16);
      o1.w = f2b(v3.z) | ((u32)f2b(v3.w) << 16);
      *(u32x4*)(As + row * 32 + cb)     = o0;
      *(u32x4*)(As + row * 32 + cb + 8) = o1;
    } else {
      const u16* A = (const u16*)Ain;
      const int f0 = w * 2;
      #pragma unroll
      for(int j = 0; j < 2; ++j){
        int e = ((f0 + j) * 64 + ln) * 8;
        gload16(A + (size_t)(m0 + (e >> 5)) * 1024 + kt + (e & 31),
                As + (size_t)(f0 + j) * 512);
      }
    }
    __syncthreads();
    // ---- compute
    bf16x8 a[4], b[4];
    #pragma unroll
    for(int mi = 0; mi < 4; ++mi)
      a[mi] = *(const bf16x8*)(As + (wr + mi*16 + c16) * 32 + g * 8);
    #pragma unroll
    for(int ni = 0; ni < 4; ++ni)
      b[ni] = *(const bf16x8*)(Bs + (wc + ni*16 + c16) * 32 + g * 8);
    #pragma unroll
    for(int mi = 0; mi < 4; ++mi)
      #pragma unroll
      for(int ni = 0; ni < 4; ++ni)
        acc[mi][ni] = __builtin_amdgcn_mfma_f32_16x16x32_bf16(a[mi], b[ni], acc[mi][ni], 0, 0, 0);
  }

  // ---- epilogue.  D: row=(lane>>4)*4+e, col=lane&15 (m89-verified)
  #pragma unroll
  for(int ni = 0; ni < 4; ++ni){
    const int colg = n0 + wc + ni*16 + c16;
    const float bv = bias[colg];
    #pragma unroll
    for(int mi = 0; mi < 4; ++mi){
      #pragma unroll
      for(int e = 0; e < 4; ++e){
        const int rowg = m0 + wr + mi*16 + g*4 + e;
        float val = acc[mi][ni][e] + bv;
        const int bb = rowg >> 11, s = rowg & 2047, h = colg >> 6, d = colg & 63;
        if (MODE == 0){
          val *= 0.125f;   // fold 1/sqrt(DK) into Q
          ((u16*)Cout)[((size_t)(bb*HH + h) * SS + s) * 64 + d] = f2b(val);
        } else if (MODE == 1){
          ((u16*)Cout)[((size_t)(bb*HH + h) * SS + s) * 64 + d] = f2b(val);
        } else if (MODE == 2){
          ((u16*)Cout)[((size_t)(bb*HH + h) * 64 + d) * SS + s] = f2b(val);
        } else {
          ((float*)Cout)[(size_t)rowg * 1024 + colg] = val;
        }
      }
    }
  }
}

// ---------------- fused attention --------------------------------------------------
// grid (S/16=128, B*H=64), 256 threads (4 waves).  Wave w owns kv slice [w*512,(w+1)*512).
// p = exp(score) stored bf16 in per-wave LDS (XOR-swizzled); softmax denominator via
// shfl-reduce + small global scratch (LDS is exactly at the 64KB static cap).
__global__ __launch_bounds__(256)
void attn_fused(const u16* __restrict__ Qb, const u16* __restrict__ Kb,
                const u16* __restrict__ Vt, float* __restrict__ attn_out,
                u16* __restrict__ AO, float* __restrict__ mlg)
{
  __shared__ __align__(16) u16 pbuf[4 * 16 * 512];  // 64KB exactly
  const int tid = threadIdx.x, w = tid >> 6, ln = tid & 63, g = ln >> 4, c = ln & 15;
  const int bh = blockIdx.y;
  const int q0 = blockIdx.x * 16;
  const int bid = bh * 128 + blockIdx.x;

  const u16* Qp = Qb + ((size_t)bh * SS + q0) * 64;
  const u16* Kp = Kb + (size_t)bh * SS * 64;
  const u16* Vp = Vt + (size_t)bh * 64 * SS;

  // Q fragments (A operand): row = lane&15, k = (lane>>4)*8+i  (+32 for second half)
  const bf16x8 aq0 = *(const bf16x8*)(Qp + c * 64 + g * 8);
  const bf16x8 aq1 = *(const bf16x8*)(Qp + c * 64 + 32 + g * 8);

  float l[4] = {0.f, 0.f, 0.f, 0.f};
  f32x4 acc_o[4] = {};
  u16* pw = pbuf + w * (16 * 512);
  const int kvbase = w * 512;

  for(int t = 0; t < 16; ++t){
    const int kv0 = kvbase + t * 32;
    const int lc  = t * 32;
    // ---- QK^T (Q pre-scaled by 1/8): B frag = K[kv0+n][k]
    const u16* kp0 = Kp + (size_t)(kv0 + c) * 64 + g * 8;
    const u16* kp1 = kp0 + 16 * 64;
    bf16x8 bk00 = *(const bf16x8*)(kp0);
    bf16x8 bk01 = *(const bf16x8*)(kp0 + 32);
    bf16x8 bk10 = *(const bf16x8*)(kp1);
    bf16x8 bk11 = *(const bf16x8*)(kp1 + 32);
    f32x4 s0 = {}, s1 = {};
    s0 = __builtin_amdgcn_mfma_f32_16x16x32_bf16(aq0, bk00, s0, 0, 0, 0);
    s0 = __builtin_amdgcn_mfma_f32_16x16x32_bf16(aq1, bk01, s0, 0, 0, 0);
    s1 = __builtin_amdgcn_mfma_f32_16x16x32_bf16(aq0, bk10, s1, 0, 0, 0);
    s1 = __builtin_amdgcn_mfma_f32_16x16x32_bf16(aq1, bk11, s1, 0, 0, 0);

    // ---- p = exp(s)  (scores bounded; skip max-subtraction), store bf16 swizzled
    #pragma unroll
    for(int e = 0; e < 4; ++e){
      const int r = g * 4 + e;
      const int sw = (r & 7) << 3;
      float p0 = __expf(s0[e]);
      float p1 = __expf(s1[e]);
      l[e] += p0 + p1;
      pw[r * 512 + ((lc + c)      ^ sw)] = f2b(p0);
      pw[r * 512 + ((lc + 16 + c) ^ sw)] = f2b(p1);
    }
    asm volatile("s_waitcnt lgkmcnt(0)" ::: "memory");
    __builtin_amdgcn_sched_barrier(0);
    // ---- PV: A frag = p[row=lane&15][k], B frag = Vt[dv][kv]
    {
      const int sw = (c & 7) << 3;
      bf16x8 ap = *(const bf16x8*)(pw + c * 512 + ((lc + g * 8) ^ sw));
      #pragma unroll
      for(int ni = 0; ni < 4; ++ni){
        bf16x8 bv = *(const bf16x8*)(Vp + (size_t)(ni * 16 + c) * SS + kv0 + g * 8);
        acc_o[ni] = __builtin_amdgcn_mfma_f32_16x16x32_bf16(ap, bv, acc_o[ni], 0, 0, 0);
      }
    }
  }

  // ---- per-row partial denominator: reduce over 16-lane group, publish to scratch
  #pragma unroll
  for(int e = 0; e < 4; ++e){
    float v = l[e];
    v += __shfl_xor(v, 1, 64);
    v += __shfl_xor(v, 2, 64);
    v += __shfl_xor(v, 4, 64);
    v += __shfl_xor(v, 8, 64);
    l[e] = v;
  }
  if(c == 0){
    #pragma unroll
    for(int e = 0; e < 4; ++e)
      mlg[(size_t)bid * 64 + w * 16 + g * 4 + e] = l[e];
  }
  __threadfence_block();
  __syncthreads();

  const float* mlb = mlg + (size_t)bid * 64;

  // ---- write normalized attention probabilities (f32, coalesced 2KB rows)
  float* aout = attn_out + ((size_t)bh * SS + q0) * SS + kvbase;
  for(int r = 0; r < 16; ++r){
    const float L = mlb[r] + mlb[16 + r] + mlb[32 + r] + mlb[48 + r];
    const float rl = 1.f / L;
    const int sw = (r & 7) << 3;
    bf16x8 pv = *(const bf16x8*)(pw + r * 512 + ((ln * 8) ^ sw));
    float4 o0, o1;
    o0.x = b2f((u16)pv[0]) * rl; o0.y = b2f((u16)pv[1]) * rl;
    o0.z = b2f((u16)pv[2]) * rl; o0.w = b2f((u16)pv[3]) * rl;
    o1.x = b2f((u16)pv[4]) * rl; o1.y = b2f((u16)pv[5]) * rl;
    o1.z = b2f((u16)pv[6]) * rl; o1.w = b2f((u16)pv[7]) * rl;
    *(float4*)(aout + (size_t)r * SS + ln * 8)     = o0;
    *(float4*)(aout + (size_t)r * SS + ln * 8 + 4) = o1;
  }
  __syncthreads();

  // ---- scale PV partials by 1/L, combine across waves (reuse pbuf as f32 buffer)
  float* redbuf = (float*)pbuf;   // [4][16][64] f32 = 16KB
  #pragma unroll
  for(int e = 0; e < 4; ++e){
    const int r = g * 4 + e;
    const float L = mlb[r] + mlb[16 + r] + mlb[32 + r] + mlb[48 + r];
    const float rl = 1.f / L;
    #pragma unroll
    for(int ni = 0; ni < 4; ++ni)
      redbuf[(w * 16 + r) * 64 + ni * 16 + c] = acc_o[ni][e] * rl;
  }
  __syncthreads();
  {
    const int e0 = tid * 4;
    float4 sA = *(const float4*)(redbuf + e0);
    float4 sB = *(const float4*)(redbuf + 1024 + e0);
    float4 sC = *(const float4*)(redbuf + 2048 + e0);
    float4 sD = *(const float4*)(redbuf + 3072 + e0);
    float4 s;
    s.x = sA.x + sB.x + sC.x + sD.x;
    s.y = sA.y + sB.y + sC.y + sD.y;
    s.z = sA.z + sB.z + sC.z + sD.z;
    s.w = sA.w + sB.w + sC.w + sD.w;
    const int r = e0 >> 6, dv = e0 & 63;
    const int bb = bh >> 4, h = bh & 15;
    u16* dst = AO + ((size_t)(bb * SS + q0 + r)) * 1024 + h * 64 + dv;
    uint2 pk;
    pk.x = f2b(s.x) | ((u32)f2b(s.y) << 16);
    pk.y = f2b(s.z) | ((u32)f2b(s.w) << 16);
    *(uint2*)dst = pk;
  }
}

// ---------------- residual + LayerNorm ---------------------------------------------
__global__ __launch_bounds__(256)
void ln_kernel(const float* __restrict__ tmp, const float* __restrict__ qin,
               const float* __restrict__ gamma, const float* __restrict__ beta,
               float* __restrict__ out)
{
  __shared__ float rs[4], rs2[4];
  const int row = blockIdx.x, tid = threadIdx.x;
  const int w = tid >> 6, ln = tid & 63;
  const float4 x4 = *(const float4*)(tmp + (size_t)row * 1024 + tid * 4);
  const float4 q4 = *(const float4*)(qin + (size_t)row * 1024 + tid * 4);
  const float xs0 = x4.x + q4.x, xs1 = x4.y + q4.y, xs2 = x4.z + q4.z, xs3 = x4.w + q4.w;
  float s  = xs0 + xs1 + xs2 + xs3;
  float s2 = xs0*xs0 + xs1*xs1 + xs2*xs2 + xs3*xs3;
  #pragma unroll
  for(int m = 1; m < 64; m <<= 1){
    s  += __shfl_xor(s,  m, 64);
    s2 += __shfl_xor(s2, m, 64);
  }
  if(ln == 0){ rs[w] = s; rs2[w] = s2; }
  __syncthreads();
  s  = rs[0]  + rs[1]  + rs[2]  + rs[3];
  s2 = rs2[0] + rs2[1] + rs2[2] + rs2[3];
  const float mu   = s * (1.f / 1024.f);
  const float var  = s2 * (1.f / 1024.f) - mu * mu;
  const float rstd = rsqrtf(var + 1e-5f);
  const float4 g4 = *(const float4*)(gamma + tid * 4);
  const float4 b4 = *(const float4*)(beta + tid * 4);
  float4 o;
  o.x = (xs0 - mu) * rstd * g4.x + b4.x;
  o.y = (xs1 - mu) * rstd * g4.y + b4.y;
  o.z = (xs2 - mu) * rstd * g4.z + b4.z;
  o.w = (xs3 - mu) * rstd * g4.w + b4.w;
  *(float4*)(out + (size_t)row * 1024 + tid * 4) = o;
}

// ------------------------------------------------------------------------------------
extern "C" void kernel_launch(void* const* d_in, const int* in_sizes, int n_in,
                              void* d_out, int out_size, void* d_ws, size_t ws_size,
                              hipStream_t stream)
{
  (void)in_sizes; (void)n_in; (void)out_size; (void)ws_size;
  const float* q     = (const float*)d_in[0];
  const float* k     = (const float*)d_in[1];
  const float* v     = (const float*)d_in[2];
  const float* Wq    = (const float*)d_in[3];
  const float* bq    = (const float*)d_in[4];
  const float* Wk    = (const float*)d_in[5];
  const float* bk    = (const float*)d_in[6];
  const float* Wv    = (const float*)d_in[7];
  const float* bv    = (const float*)d_in[8];
  const float* Wo    = (const float*)d_in[9];
  const float* bo    = (const float*)d_in[10];
  const float* gamma = (const float*)d_in[11];
  const float* beta  = (const float*)d_in[12];

  char* p = (char*)d_ws;
  auto alloc = [&](size_t bytes) -> void* {
    void* r = (void*)p; p += (bytes + 255) & ~(size_t)255; return r;
  };
  const size_t NTOK = (size_t)BB * SS;           // 8192
  u16* WtQ  = (u16*)alloc((size_t)DD * DD * 2);
  u16* WtK  = (u16*)alloc((size_t)DD * DD * 2);
  u16* WtV  = (u16*)alloc((size_t)DD * DD * 2);
  u16* WtO  = (u16*)alloc((size_t)DD * DD * 2);
  u16* Qb   = (u16*)alloc(NTOK * DD * 2);
  u16* Kb   = (u16*)alloc(NTOK * DD * 2);
  u16* Vtb  = (u16*)alloc(NTOK * DD * 2);
  u16* AO   = (u16*)alloc(NTOK * DD * 2);
  float* tmp = (float*)alloc(NTOK * DD * 4);
  float* mlg = (float*)alloc((size_t)8192 * 64 * 4);

  float* out0 = (float*)d_out;
  float* attn = out0 + NTOK * DD;                // [B,H,S,S]

  const dim3 tb(32, 8);
  transpose_cvt<<<dim3(32, 32), tb, 0, stream>>>(Wq, WtQ);
  transpose_cvt<<<dim3(32, 32), tb, 0, stream>>>(Wk, WtK);
  transpose_cvt<<<dim3(32, 32), tb, 0, stream>>>(Wv, WtV);
  transpose_cvt<<<dim3(32, 32), tb, 0, stream>>>(Wo, WtO);

  gemm128<0><<<dim3(8, 64), 256, 0, stream>>>(q, WtQ, bq, Qb);
  gemm128<1><<<dim3(8, 64), 256, 0, stream>>>(k, WtK, bk, Kb);
  gemm128<2><<<dim3(8, 64), 256, 0, stream>>>(v, WtV, bv, Vtb);

  attn_fused<<<dim3(128, 64), 256, 0, stream>>>(Qb, Kb, Vtb, attn, AO, mlg);

  gemm128<3><<<dim3(8, 64), 256, 0, stream>>>(AO, WtO, bo, tmp);
  ln_kernel<<<dim3(8192), 256, 0, stream>>>(tmp, q, gamma, beta, out0);
}